// Round 3
// baseline (338.679 us; speedup 1.0000x reference)
//
#include <hip/hip_runtime.h>
#include <math.h>

#define ROWS 18496          // bt*J*N = 64*17*17
#define SCALE 0.17677669529663687f  // 1/sqrt(32)

typedef unsigned short ushort_t;
typedef __attribute__((ext_vector_type(8))) short short8;
typedef __attribute__((ext_vector_type(4))) float f32x4;

__device__ __forceinline__ void fma4(float4& d, float s, const float4& v) {
    d.x = fmaf(s, v.x, d.x); d.y = fmaf(s, v.y, d.y);
    d.z = fmaf(s, v.z, d.z); d.w = fmaf(s, v.w, d.w);
}

__device__ __forceinline__ ushort_t f2bf(float x) {
    union { float f; unsigned u; } v; v.f = x;
    unsigned r = v.u + 0x7fffu + ((v.u >> 16) & 1u);
    return (ushort_t)(r >> 16);
}
__device__ __forceinline__ float bf2f(ushort_t b) {
    union { unsigned u; float f; } v; v.u = ((unsigned)b) << 16; return v.f;
}

__device__ __forceinline__ void gl_lds16(const void* g, void* l) {
    __builtin_amdgcn_global_load_lds(
        (const __attribute__((address_space(1))) void*)g,
        (__attribute__((address_space(3))) void*)l, 16, 0, 0);
}

// ---------------- merged conversion kernel ----------------------------
// blocks [0,4624): x (18496x256 f32) -> xhi/xlo bf16
// blocks [4624,5904): Wqkv -> transposed+permuted bf16 [o][k]
__global__ __launch_bounds__(256) void k_cvt_xw(
    const float4* __restrict__ x, ushort4* __restrict__ xhi, ushort4* __restrict__ xlo,
    const float* __restrict__ W, ushort_t* __restrict__ bh, ushort_t* __restrict__ bl)
{
    if (blockIdx.x < 4624) {
        int i = blockIdx.x * 256 + threadIdx.x;
        float4 v = x[i];
        ushort4 h, l;
        h.x = f2bf(v.x); l.x = f2bf(v.x - bf2f(h.x));
        h.y = f2bf(v.y); l.y = f2bf(v.y - bf2f(h.y));
        h.z = f2bf(v.z); l.z = f2bf(v.z - bf2f(h.z));
        h.w = f2bf(v.w); l.w = f2bf(v.w - bf2f(h.w));
        xhi[i] = h; xlo[i] = l;
    } else {
        int o = blockIdx.x - 4624;   // 0..1279
        int kk = threadIdx.x;        // 0..255
        int col = (o & 255) * 5 + (o >> 8);
        float v = W[(size_t)kk * 1280 + col];
        ushort_t hh = f2bf(v);
        bh[(size_t)o * 256 + kk] = hh;
        bl[(size_t)o * 256 + kk] = f2bf(v - bf2f(hh));
    }
}

// Wp (768x256 f32) -> transposed bf16 [n][k]
__global__ __launch_bounds__(256) void k_cvt_wp(
    const float* __restrict__ W, ushort_t* __restrict__ bh, ushort_t* __restrict__ bl)
{
    int n = blockIdx.x;          // 0..255
    for (int k = threadIdx.x; k < 768; k += 256) {
        float v = W[(size_t)k * 256 + n];
        ushort_t h = f2bf(v);
        bh[(size_t)n * 768 + k] = h;
        bl[(size_t)n * 768 + k] = f2bf(v - bf2f(h));
    }
}

// ---------------- split-bf16 MFMA GEMM (unchanged structure) ----------
template<int BM, int BN, int K, int MODE>
__global__ __launch_bounds__(256) void k_gemm(
    const ushort_t* __restrict__ Ahi, const ushort_t* __restrict__ Alo,
    const ushort_t* __restrict__ Bhi, const ushort_t* __restrict__ Blo,
    const float* __restrict__ aux,
    float* __restrict__ out)
{
    constexpr int MT = BM / 32;
    constexpr int NT = BN / 32;
    __shared__ __attribute__((aligned(16))) ushort_t sAh[BM * 32];
    __shared__ __attribute__((aligned(16))) ushort_t sAl[BM * 32];
    __shared__ __attribute__((aligned(16))) ushort_t sBh[BN * 32];
    __shared__ __attribute__((aligned(16))) ushort_t sBl[BN * 32];

    const int t = threadIdx.x;
    const int lane = t & 63;
    const int ln = lane & 15, quad = lane >> 4;
    const int wave = t >> 6;
    const int wm = wave >> 1, wn = wave & 1;
    const int m0 = blockIdx.y * BM, n0 = blockIdx.x * BN;

    f32x4 acc[MT][NT];
#pragma unroll
    for (int i = 0; i < MT; ++i)
#pragma unroll
        for (int j = 0; j < NT; ++j) acc[i][j] = (f32x4){0.f, 0.f, 0.f, 0.f};

    for (int kb = 0; kb < K; kb += 32) {
        __syncthreads();
#pragma unroll
        for (int s = t; s < BM * 4; s += 256) {
            int row = s >> 2, kc = s & 3;
            int gr = m0 + row; if (gr > ROWS - 1) gr = ROWS - 1;
            size_t gb = ((size_t)gr * K + kb) * 2 + kc * 16;
            int lb = (s & ~63) * 16;
            gl_lds16((const char*)Ahi + gb, (char*)sAh + lb);
            gl_lds16((const char*)Alo + gb, (char*)sAl + lb);
        }
#pragma unroll
        for (int s = t; s < BN * 4; s += 256) {
            int row = s >> 2, kc = s & 3;
            size_t gb = ((size_t)(n0 + row) * K + kb) * 2 + kc * 16;
            int lb = (s & ~63) * 16;
            gl_lds16((const char*)Bhi + gb, (char*)sBh + lb);
            gl_lds16((const char*)Blo + gb, (char*)sBl + lb);
        }
        __syncthreads();

        short8 ah[MT], al[MT], bh[NT], bl[NT];
#pragma unroll
        for (int i = 0; i < MT; ++i) {
            int off = (wm * (BM / 2) + i * 16 + ln) * 32 + quad * 8;
            ah[i] = *(const short8*)&sAh[off];
            al[i] = *(const short8*)&sAl[off];
        }
#pragma unroll
        for (int j = 0; j < NT; ++j) {
            int off = (wn * (BN / 2) + j * 16 + ln) * 32 + quad * 8;
            bh[j] = *(const short8*)&sBh[off];
            bl[j] = *(const short8*)&sBl[off];
        }
#pragma unroll
        for (int i = 0; i < MT; ++i)
#pragma unroll
            for (int j = 0; j < NT; ++j) {
                acc[i][j] = __builtin_amdgcn_mfma_f32_16x16x32_bf16(ah[i], bh[j], acc[i][j], 0, 0, 0);
                acc[i][j] = __builtin_amdgcn_mfma_f32_16x16x32_bf16(ah[i], bl[j], acc[i][j], 0, 0, 0);
                acc[i][j] = __builtin_amdgcn_mfma_f32_16x16x32_bf16(al[i], bh[j], acc[i][j], 0, 0, 0);
            }
    }

#pragma unroll
    for (int i = 0; i < MT; ++i) {
#pragma unroll
        for (int r = 0; r < 4; ++r) {
            int gm = m0 + wm * (BM / 2) + i * 16 + quad * 4 + r;
            if (gm >= ROWS) continue;
            if (MODE == 0) {
                int jn = gm % 289;
                const float* Mrow = &aux[(size_t)jn * 256];
#pragma unroll
                for (int j = 0; j < NT; ++j) {
                    int gn = n0 + wn * (BN / 2) + j * 16 + ln;
                    out[(size_t)gm * 1280 + gn] = acc[i][j][r] * Mrow[gn & 255];
                }
            } else {
#pragma unroll
                for (int j = 0; j < NT; ++j) {
                    int gn = n0 + wn * (BN / 2) + j * 16 + ln;
                    out[(size_t)gm * 256 + gn] = acc[i][j][r] + aux[gn];
                }
            }
        }
    }
}

// ---------------- K2a v2: scores + 4 softmaxes, one block per (b,h) ------
// LDS holds only the K tile (289x32 fp32, XOR-swizzled chunks) + sym biases.
// 170 lanes: lane = (matrix m in 0..33) x (row-chunk rc in 0..4).
// Each lane computes 4 score rows (register-tiled), then both softmaxes
// fully in registers. One __syncthreads total.
__global__ __launch_bounds__(256) void k_scores2(
    const float* __restrict__ qkv5,
    const float* __restrict__ A_s, const float* __restrict__ A_v,
    const float* __restrict__ adjS, const float* __restrict__ adjV,
    float* __restrict__ attS, float* __restrict__ attV,
    float* __restrict__ attS2, float* __restrict__ attV2)
{
    __shared__ __attribute__((aligned(16))) float ksh[289 * 32];
    __shared__ float biasS[289];
    __shared__ float biasV[289];
    const int t  = threadIdx.x;
    const int bh = blockIdx.x;
    const int b  = bh >> 3, h = bh & 7;
    const size_t rowbase = (size_t)b * 289;

    // stage K tile (cols 256..511 of qkv5), chunk-swizzled
    for (int idx = t; idx < 2312; idx += 256) {
        int p = idx >> 3, c = idx & 7;
        float4 v = *(const float4*)&qkv5[(rowbase + p) * 1280 + 256 + h * 32 + c * 4];
        int cs = c ^ (p & 7);
        *(float4*)&ksh[p * 32 + cs * 4] = v;
    }
    // symmetrized biases
    for (int idx = t; idx < 578; idx += 256) {
        int f = idx / 289, rem = idx % 289;
        int jj = rem / 17, kk = rem % 17;
        if (f == 0)
            biasS[rem] = 0.5f * ((A_s[jj*17+kk] + adjS[jj*17+kk]) + (A_s[kk*17+jj] + adjS[kk*17+jj]));
        else
            biasV[rem] = 0.5f * ((A_v[jj*17+kk] + adjV[jj*17+kk]) + (A_v[kk*17+jj] + adjV[kk*17+jj]));
    }
    __syncthreads();

    if (t >= 170) return;
    const int m  = t / 5, rc = t % 5;
    const int f  = m / 17, i = m % 17;
    const int r0 = (rc < 2) ? rc * 4 : 8 + (rc - 2) * 3;
    const int nr = (rc < 2) ? 4 : 3;

    int pq[4];
#pragma unroll
    for (int rr = 0; rr < 4; ++rr) {
        int row = r0 + rr; if (row > 16) row = 16;
        pq[rr] = f ? (i * 17 + row) : (row * 17 + i);
    }

    float sc[4][17];
#pragma unroll
    for (int rr = 0; rr < 4; ++rr)
#pragma unroll
        for (int kk = 0; kk < 17; ++kk) sc[rr][kk] = 0.f;

#pragma unroll
    for (int c = 0; c < 8; ++c) {
        float4 q4[4];
#pragma unroll
        for (int rr = 0; rr < 4; ++rr)
            q4[rr] = *(const float4*)&qkv5[(rowbase + pq[rr]) * 1280 + h * 32 + c * 4];
#pragma unroll
        for (int kk = 0; kk < 17; ++kk) {
            int pk = f ? (i * 17 + kk) : (kk * 17 + i);
            float4 kv = *(const float4*)&ksh[pk * 32 + ((c ^ (pk & 7)) * 4)];
#pragma unroll
            for (int rr = 0; rr < 4; ++rr) {
                sc[rr][kk] = fmaf(q4[rr].x, kv.x, sc[rr][kk]);
                sc[rr][kk] = fmaf(q4[rr].y, kv.y, sc[rr][kk]);
                sc[rr][kk] = fmaf(q4[rr].z, kv.z, sc[rr][kk]);
                sc[rr][kk] = fmaf(q4[rr].w, kv.w, sc[rr][kk]);
            }
        }
    }

    float* dstU = f ? attV : attS;
    float* dstB = f ? attV2 : attS2;
    const float* bias = f ? biasV : biasS;

    for (int rr = 0; rr < nr; ++rr) {
        int row = r0 + rr;
        size_t base = (size_t)bh * 4913 + i * 289 + row * 17;
        float v[17];
#pragma unroll
        for (int kk = 0; kk < 17; ++kk) v[kk] = sc[rr][kk] * SCALE;
        // unbiased softmax
        float mx = v[0];
#pragma unroll
        for (int kk = 1; kk < 17; ++kk) mx = fmaxf(mx, v[kk]);
        float e[17], sum = 0.f;
#pragma unroll
        for (int kk = 0; kk < 17; ++kk) { e[kk] = expf(v[kk] - mx); sum += e[kk]; }
        float inv = 1.f / sum;
#pragma unroll
        for (int kk = 0; kk < 17; ++kk) dstU[base + kk] = e[kk] * inv;
        // biased softmax
#pragma unroll
        for (int kk = 0; kk < 17; ++kk) v[kk] += bias[row * 17 + kk];
        mx = v[0];
#pragma unroll
        for (int kk = 1; kk < 17; ++kk) mx = fmaxf(mx, v[kk]);
        sum = 0.f;
#pragma unroll
        for (int kk = 0; kk < 17; ++kk) { e[kk] = expf(v[kk] - mx); sum += e[kk]; }
        inv = 1.f / sum;
#pragma unroll
        for (int kk = 0; kk < 17; ++kk) dstB[base + kk] = e[kk] * inv;
    }
}

__device__ __forceinline__ void store_hilo(ushort_t* yhi, ushort_t* ylo,
                                           size_t off, const float4& a)
{
    ushort4 h, l;
    h.x = f2bf(a.x); l.x = f2bf(a.x - bf2f(h.x));
    h.y = f2bf(a.y); l.y = f2bf(a.y - bf2f(h.y));
    h.z = f2bf(a.z); l.z = f2bf(a.z - bf2f(h.z));
    h.w = f2bf(a.w); l.w = f2bf(a.w - bf2f(h.w));
    *(ushort4*)&yhi[off] = h;
    *(ushort4*)&ylo[off] = l;
}

// ---------------- K2b: x_vs and x_vv -> y cols 256..767 (bf16 hi/lo) -----
__global__ __launch_bounds__(256) void k_xvs_xvv(
    const float* __restrict__ qkv5,
    const float* __restrict__ attS2, const float* __restrict__ attV2,
    ushort_t* __restrict__ yhi, ushort_t* __restrict__ ylo)
{
    __shared__ __attribute__((aligned(16))) float att2[4913];
    __shared__ __attribute__((aligned(16))) float vbuf[9248];
    const int t  = threadIdx.x;
    const int bh = blockIdx.x;
    const int b  = bh >> 3, h = bh & 7;
    const int pq = t >> 3, c4 = (t & 7) * 4;

    for (int idx = t; idx < 4913; idx += 256) att2[idx] = attS2[(size_t)bh * 4913 + idx];
    for (int idx = t; idx < 2312; idx += 256) {
        int p = idx >> 3, cc = (idx & 7) * 4;
        *(float4*)&vbuf[p * 32 + cc] =
            *(const float4*)&qkv5[(((size_t)b * 17 + p / 17) * 17 + p % 17) * 1280 + 512 + h * 32 + cc];
    }
    __syncthreads();
    for (int pi = 0; pi < 10; ++pi) {
        int p = pi * 32 + pq;
        if (p < 289) {
            int j = p / 17, n = p % 17;
            const float* arow = &att2[(n * 17 + j) * 17];
            float4 acc = {0,0,0,0};
            for (int kk = 0; kk < 17; ++kk) {
                float4 v = *(const float4*)&vbuf[(kk * 17 + n) * 32 + c4];
                fma4(acc, arow[kk], v);
            }
            size_t r = ((size_t)b * 17 + j) * 17 + n;
            store_hilo(yhi, ylo, r * 768 + 256 + h * 32 + c4, acc);
        }
    }
    __syncthreads();
    for (int idx = t; idx < 4913; idx += 256) att2[idx] = attV2[(size_t)bh * 4913 + idx];
    for (int idx = t; idx < 2312; idx += 256) {
        int p = idx >> 3, cc = (idx & 7) * 4;
        *(float4*)&vbuf[p * 32 + cc] =
            *(const float4*)&qkv5[(((size_t)b * 17 + p / 17) * 17 + p % 17) * 1280 + 768 + h * 32 + cc];
    }
    __syncthreads();
    for (int pi = 0; pi < 10; ++pi) {
        int p = pi * 32 + pq;
        if (p < 289) {
            int j = p / 17, n = p % 17;
            const float* arow = &att2[(j * 17 + n) * 17];
            float4 acc = {0,0,0,0};
            for (int mm = 0; mm < 17; ++mm) {
                float4 v = *(const float4*)&vbuf[(j * 17 + mm) * 32 + c4];
                fma4(acc, arow[mm], v);
            }
            size_t r = ((size_t)b * 17 + j) * 17 + n;
            store_hilo(yhi, ylo, r * 768 + 512 + h * 32 + c4, acc);
        }
    }
}

// ---------------- K2c: x_vsv (bilinear combine) -> y cols 0..255 ---------
__global__ __launch_bounds__(256) void k_xvsv(
    const float* __restrict__ qkv5, const float* __restrict__ attS,
    const float* __restrict__ attV,
    ushort_t* __restrict__ yhi, ushort_t* __restrict__ ylo)
{
    __shared__ __attribute__((aligned(16))) float vbuf[9248];
    const int t  = threadIdx.x;
    const int bh = blockIdx.x;
    const int b  = bh >> 3, h = bh & 7;
    const int pq = t >> 3, c4 = (t & 7) * 4;
    const float* aSg = attS + (size_t)bh * 4913;
    const float* aVg = attV + (size_t)bh * 4913;

    for (int idx = t; idx < 2312; idx += 256) {
        int p = idx >> 3, cc = (idx & 7) * 4;
        *(float4*)&vbuf[p * 32 + cc] =
            *(const float4*)&qkv5[(((size_t)b * 17 + p / 17) * 17 + p % 17) * 1280 + 1024 + h * 32 + cc];
    }
    __syncthreads();

    for (int pi = 0; pi < 5; ++pi) {
        int p0 = pi * 64 + pq;
        int p1 = p0 + 32;
        bool hasp1 = (p1 < 289);
        int p1c = hasp1 ? p1 : 0;
        int j0 = p0 / 17, n0 = p0 % 17;
        int j1 = p1c / 17, n1 = p1c % 17;
        float b0r[17], b1r[17];
        const float* bv0 = &aVg[(j0 * 17 + n0) * 17];
        const float* bv1 = &aVg[(j1 * 17 + n1) * 17];
#pragma unroll
        for (int m = 0; m < 17; ++m) { b0r[m] = bv0[m]; b1r[m] = bv1[m]; }
        const float* ap0 = &aSg[(n0 * 17 + j0) * 17];
        const float* ap1 = &aSg[(n1 * 17 + j1) * 17];
        float4 acc0 = {0,0,0,0}, acc1 = {0,0,0,0};
        for (int kk = 0; kk < 17; ++kk) {
            float a0 = ap0[kk], a1 = ap1[kk];
            float4 t0 = {0,0,0,0}, t1 = {0,0,0,0};
            const float* vrow = &vbuf[kk * 544 + c4];
#pragma unroll
            for (int m = 0; m < 17; ++m) {
                float4 v = *(const float4*)&vrow[m * 32];
                fma4(t0, b0r[m], v);
                fma4(t1, b1r[m], v);
            }
            fma4(acc0, a0, t0);
            fma4(acc1, a1, t1);
        }
        size_t r0 = ((size_t)b * 17 + j0) * 17 + n0;
        store_hilo(yhi, ylo, r0 * 768 + h * 32 + c4, acc0);
        if (hasp1) {
            size_t r1 = ((size_t)b * 17 + j1) * 17 + n1;
            store_hilo(yhi, ylo, r1 * 768 + h * 32 + c4, acc1);
        }
    }
}

extern "C" void kernel_launch(void* const* d_in, const int* in_sizes, int n_in,
                              void* d_out, int out_size, void* d_ws, size_t ws_size,
                              hipStream_t stream)
{
    const float* x    = (const float*)d_in[0];
    const float* A_s  = (const float*)d_in[1];
    const float* A_v  = (const float*)d_in[2];
    const float* Wqkv = (const float*)d_in[3];
    const float* Wp   = (const float*)d_in[4];
    const float* bp   = (const float*)d_in[5];
    const float* M    = (const float*)d_in[6];
    const float* adjS = (const float*)d_in[7];
    const float* adjV = (const float*)d_in[8];
    float* out = (float*)d_out;

    char* w = (char*)d_ws;
    float*    qkv5  = (float*)w;
    ushort_t* wph   = (ushort_t*)w;                       // written after combines
    ushort_t* wpl   = (ushort_t*)(w + 393216);
    float* attS  = (float*)(w + 94699520);
    float* attV  = (float*)(w + 94699520 + 10061824);
    float* attS2 = (float*)(w + 94699520 + 2 * (size_t)10061824);
    float* attV2 = (float*)(w + 94699520 + 3 * (size_t)10061824);
    char* R = w + 134946816;
    ushort_t* xhi = (ushort_t*)R;
    ushort_t* xlo = (ushort_t*)(R + 9469952);
    ushort_t* wqh = (ushort_t*)(R + 18939904);
    ushort_t* wql = (ushort_t*)(R + 19595264);
    ushort_t* yhi = (ushort_t*)R;                         // alias (after k_gemm qkv done)
    ushort_t* ylo = (ushort_t*)(R + 28422144);

    k_cvt_xw<<<dim3(5904), 256, 0, stream>>>((const float4*)x, (ushort4*)xhi, (ushort4*)xlo,
                                             Wqkv, wqh, wql);
    k_gemm<128, 128, 256, 0><<<dim3(10, 145), 256, 0, stream>>>(xhi, xlo, wqh, wql, M, qkv5);
    k_scores2<<<dim3(512), 256, 0, stream>>>(qkv5, A_s, A_v, adjS, adjV,
                                             attS, attV, attS2, attV2);
    k_xvs_xvv<<<dim3(512), 256, 0, stream>>>(qkv5, attS2, attV2, yhi, ylo);
    k_xvsv<<<dim3(512), 256, 0, stream>>>(qkv5, attS, attV, yhi, ylo);
    k_cvt_wp<<<dim3(256), 256, 0, stream>>>(Wp, wph, wpl);
    k_gemm<128, 64, 768, 1><<<dim3(4, 145), 256, 0, stream>>>(yhi, ylo, wph, wpl, bp, out);
}